// Round 1
// baseline (280.505 us; speedup 1.0000x reference)
//
#include <hip/hip_runtime.h>
#include <math.h>

#define E_  8
#define H_  2048
#define I_  768
#define T_  1024
#define K_  2
#define TK_ 2048
#define GU_ 1536   // 2*I

typedef short  short8 __attribute__((ext_vector_type(8)));
typedef __bf16 bf16x8 __attribute__((ext_vector_type(8)));
typedef float  f32x4  __attribute__((ext_vector_type(4)));

static __device__ __forceinline__ short f2bf(float f) {
  union { float f; unsigned u; } v; v.f = f;
  unsigned r = (v.u + 0x7fffu + ((v.u >> 16) & 1u)) >> 16;
  return (short)r;
}

// pack two floats -> two bf16 in one u32 (round-half-up + v_perm)
static __device__ __forceinline__ unsigned pk2bf(float a, float b) {
  unsigned ua = __float_as_uint(a) + 0x8000u;
  unsigned ub = __float_as_uint(b) + 0x8000u;
  return __builtin_amdgcn_perm(ub, ua, 0x07060302u);  // lo=hi16(ua), hi=hi16(ub)
}

#define GLOAD_LDS16(g, l)                                                   \
  __builtin_amdgcn_global_load_lds(                                         \
      (const __attribute__((address_space(1))) void*)(g),                   \
      (__attribute__((address_space(3))) void*)(l), 16, 0, 0)

#define MFMA_BF16_16x16x32 __builtin_amdgcn_mfma_f32_16x16x32_bf16

// Fragment read: row-major [row][64], phys octet = oct ^ (row&7).
// Used for both A (128 rows) and B (32 rows) tiles now.
static __device__ __forceinline__ bf16x8 frag_ld(const unsigned short* base,
                                                 int row, int oct) {
  return *(const bf16x8*)(base + row * 64 + ((oct ^ (row & 7)) * 8));
}

// --------------------------- prep: X cast + out zero + routing --------------
__global__ __launch_bounds__(256) void prep_kernel(
    const float* __restrict__ X, unsigned short* __restrict__ Xb,
    float* __restrict__ out,
    const int* __restrict__ sel, int* __restrict__ offs,
    int* __restrict__ rows) {
  __shared__ int cnt[E_], cur[E_], loff[E_ + 1];
  if (blockIdx.x < 2048) {
    int i = blockIdx.x * 256 + threadIdx.x;     // one float4 each (T*H/4 total)
    float4 v = ((const float4*)X)[i];
    unsigned p0 = pk2bf(v.x, v.y), p1 = pk2bf(v.z, v.w);
    ((uint2*)Xb)[i] = make_uint2(p0, p1);
    ((float4*)out)[i] = make_float4(0.f, 0.f, 0.f, 0.f);  // out: same elem count
    return;
  }
  int t = threadIdx.x;
  if (t < E_) { cnt[t] = 0; cur[t] = 0; }
  __syncthreads();
  for (int p = t; p < TK_; p += 256) atomicAdd(&cnt[sel[p]], 1);
  __syncthreads();
  if (t == 0) {
    int s = 0;
    for (int e = 0; e < E_; ++e) { loff[e] = s; s += cnt[e]; }
    loff[E_] = s;
  }
  __syncthreads();
  if (t <= E_) offs[t] = loff[t];
  for (int p = t; p < TK_; p += 256) {
    int e = sel[p];
    int pos = loff[e] + atomicAdd(&cur[e], 1);
    rows[pos] = p;
  }
}

// --------------------------------------------------- fc1 (MFMA) + swiglu ----
// BM=128 rows, BN=32 B-cols (16 gate + 16 up), BK=64, double-buffer.
// 4 waves, each wave = 32 rows x 32 B-cols (acc[2][2]).
// A: bf16 gathered via global_load_lds (XOR-octet layout).
// B: fp32 [k][n] direct, in-reg cast, same XOR-octet 64-pitch layout as A.
// LDS = 32KB(A) + 8KB(B) = 40960 B -> 4 blocks/CU, 16 waves/CU.
// Grid: x = 48 (16 gate cols each), y = 8 experts * 16 slots of 128 rows.
__global__ __launch_bounds__(256, 4) void fc1_mfma(
    const unsigned short* __restrict__ Xb, const float* __restrict__ GUP,
    const int* __restrict__ offs, const int* __restrict__ rows,
    unsigned short* __restrict__ act) {
  __shared__ __align__(16) unsigned short As[2][128 * 64];  // 32 KB
  __shared__ __align__(16) unsigned short Bs[2][32 * 64];   // 8 KB

  int e    = blockIdx.y >> 4;
  int rbeg = offs[e], rend = offs[e + 1];
  int row0 = rbeg + (blockIdx.y & 15) * 128;
  if (row0 >= rend) return;
  int c0 = blockIdx.x * 16;                  // gate col base (up base = I_+c0)

  int tid = threadIdx.x, lane = tid & 63, w = tid >> 6;
  int rl  = lane >> 3;                    // 0..7
  int oct = (lane & 7) ^ rl;              // A-side global octet swizzle

  // A: wave w owns rows w*32 .. w*32+31, staged as 4 glls of 8 rows.
  const unsigned short* agp[4];
#pragma unroll
  for (int i = 0; i < 4; ++i) {
    int arow = row0 + w * 32 + i * 8 + rl;
    int aidx = arow < rend ? arow : rend - 1;
    agp[i] = Xb + (size_t)(rows[aidx] >> 1) * H_ + oct * 8;
  }
  auto issueA = [&](int buf, int k0) {
#pragma unroll
    for (int i = 0; i < 4; ++i)
      GLOAD_LDS16(agp[i] + k0, &As[buf][0] + (w * 32 + i * 8) * 64);
  };

  // B: thread covers 2 consecutive k-rows x 4 cols. Local n: 0-15 gate, 16-31 up.
  int q = tid & 7, kt2 = tid >> 3;        // q: col-quad, kt2: k-pair 0..31
  int gcol = (q < 4) ? (c0 + q * 4) : (I_ + c0 + (q - 4) * 4);
  const float* gupe = GUP + (size_t)e * H_ * GU_ + gcol;

  float4 vb[2];
  auto loadB = [&](int k0) {
#pragma unroll
    for (int i = 0; i < 2; ++i)
      vb[i] = *(const float4*)(gupe + (size_t)(k0 + kt2 * 2 + i) * GU_);
  };
  auto writeB = [&](int buf) {
#pragma unroll
    for (int j = 0; j < 4; ++j) {
      int n = q * 4 + j;
      unsigned u = pk2bf(((const float*)&vb[0])[j], ((const float*)&vb[1])[j]);
      int sw = (kt2 >> 2) ^ (n & 7);
      *(unsigned*)(&Bs[buf][0] + n * 64 + sw * 8 + ((kt2 * 2) & 7)) = u;
    }
  };

  int m = lane & 15, qf = lane >> 4;
  f32x4 acc[2][2] = {};

  issueA(0, 0);
  loadB(0);
  writeB(0);
  int cur = 0;
  const int niter = H_ / 64;
#pragma unroll 1
  for (int it = 0; it < niter; ++it) {
    __syncthreads();                      // buf[cur] ready
    if (it + 1 < niter) { issueA(cur ^ 1, (it + 1) * 64); loadB((it + 1) * 64); }
    const unsigned short* a_ = &As[cur][0];
    const unsigned short* b_ = &Bs[cur][0];
#pragma unroll
    for (int kk = 0; kk < 2; ++kk) {
      int o = kk * 4 + qf;
      bf16x8 af0 = frag_ld(a_, w * 32 + m,      o);
      bf16x8 af1 = frag_ld(a_, w * 32 + 16 + m, o);
      bf16x8 b0  = frag_ld(b_, m,      o);      // gate cols
      bf16x8 b1  = frag_ld(b_, 16 + m, o);      // up cols
      acc[0][0] = MFMA_BF16_16x16x32(af0, b0, acc[0][0], 0, 0, 0);
      acc[0][1] = MFMA_BF16_16x16x32(af0, b1, acc[0][1], 0, 0, 0);
      acc[1][0] = MFMA_BF16_16x16x32(af1, b0, acc[1][0], 0, 0, 0);
      acc[1][1] = MFMA_BF16_16x16x32(af1, b1, acc[1][1], 0, 0, 0);
    }
    if (it + 1 < niter) writeB(cur ^ 1);
    cur ^= 1;
  }

  // epilogue: act = silu(gate)*up ; acc[.][0]=gate(col c0+m), acc[.][1]=up.
#pragma unroll
  for (int mt = 0; mt < 2; ++mt)
#pragma unroll
    for (int r = 0; r < 4; ++r) {
      int prow = row0 + w * 32 + mt * 16 + qf * 4 + r;
      if (prow < rend) {
        float gv = acc[mt][0][r], uv = acc[mt][1][r];
        float a = gv / (1.0f + __expf(-gv)) * uv;
        act[(size_t)prow * I_ + c0 + m] = (unsigned short)f2bf(a);
      }
    }
}

// ------------------------------------- fc2 (MFMA) + fused weighted combine --
// BM=128, BN=32 out cols, BK=64, double-buffer; epilogue atomics into out.
// 4 waves x (32 rows x 32 cols). LDS 40960 B -> 4 blocks/CU.
// Grid: x = 64, y = 8 experts * 16 slots of 128 rows.
__global__ __launch_bounds__(256, 4) void fc2_mfma(
    const unsigned short* __restrict__ act, const float* __restrict__ DWN,
    const float* __restrict__ RW,
    const int* __restrict__ offs, const int* __restrict__ rows,
    float* __restrict__ out) {
  __shared__ __align__(16) unsigned short As[2][128 * 64];
  __shared__ __align__(16) unsigned short Bs[2][32 * 64];

  int e    = blockIdx.y >> 4;
  int rbeg = offs[e], rend = offs[e + 1];
  int row0 = rbeg + (blockIdx.y & 15) * 128;
  if (row0 >= rend) return;
  int c0 = blockIdx.x * 32;

  int tid = threadIdx.x, lane = tid & 63, w = tid >> 6;
  int rl  = lane >> 3;
  int oct = (lane & 7) ^ rl;

  const unsigned short* agp[4];
#pragma unroll
  for (int i = 0; i < 4; ++i) {
    int arow = row0 + w * 32 + i * 8 + rl;
    int aidx = arow < rend ? arow : rend - 1;
    agp[i] = act + (size_t)aidx * I_ + oct * 8;
  }
  auto issueA = [&](int buf, int k0) {
#pragma unroll
    for (int i = 0; i < 4; ++i)
      GLOAD_LDS16(agp[i] + k0, &As[buf][0] + (w * 32 + i * 8) * 64);
  };

  int q = tid & 7, kt2 = tid >> 3;
  const float* dwe = DWN + (size_t)e * I_ * H_ + c0 + q * 4;

  float4 vb[2];
  auto loadB = [&](int k0) {
#pragma unroll
    for (int i = 0; i < 2; ++i)
      vb[i] = *(const float4*)(dwe + (size_t)(k0 + kt2 * 2 + i) * H_);
  };
  auto writeB = [&](int buf) {
#pragma unroll
    for (int j = 0; j < 4; ++j) {
      int n = q * 4 + j;
      unsigned u = pk2bf(((const float*)&vb[0])[j], ((const float*)&vb[1])[j]);
      int sw = (kt2 >> 2) ^ (n & 7);
      *(unsigned*)(&Bs[buf][0] + n * 64 + sw * 8 + ((kt2 * 2) & 7)) = u;
    }
  };

  int m = lane & 15, qf = lane >> 4;
  f32x4 acc[2][2] = {};

  issueA(0, 0);
  loadB(0);
  writeB(0);
  int cur = 0;
  const int niter = I_ / 64;
#pragma unroll 1
  for (int it = 0; it < niter; ++it) {
    __syncthreads();
    if (it + 1 < niter) { issueA(cur ^ 1, (it + 1) * 64); loadB((it + 1) * 64); }
    const unsigned short* a_ = &As[cur][0];
    const unsigned short* b_ = &Bs[cur][0];
#pragma unroll
    for (int kk = 0; kk < 2; ++kk) {
      int o = kk * 4 + qf;
      bf16x8 af0 = frag_ld(a_, w * 32 + m,      o);
      bf16x8 af1 = frag_ld(a_, w * 32 + 16 + m, o);
      bf16x8 b0  = frag_ld(b_, m,      o);
      bf16x8 b1  = frag_ld(b_, 16 + m, o);
      acc[0][0] = MFMA_BF16_16x16x32(af0, b0, acc[0][0], 0, 0, 0);
      acc[0][1] = MFMA_BF16_16x16x32(af0, b1, acc[0][1], 0, 0, 0);
      acc[1][0] = MFMA_BF16_16x16x32(af1, b0, acc[1][0], 0, 0, 0);
      acc[1][1] = MFMA_BF16_16x16x32(af1, b1, acc[1][1], 0, 0, 0);
    }
    if (it + 1 < niter) writeB(cur ^ 1);
    cur ^= 1;
  }

  // epilogue: out[token] += rw * fc2  (out zeroed by prep)
#pragma unroll
  for (int mt = 0; mt < 2; ++mt)
#pragma unroll
    for (int r = 0; r < 4; ++r) {
      int prow = row0 + w * 32 + mt * 16 + qf * 4 + r;
      if (prow < rend) {
        int pair = rows[prow];
        float rw = RW[pair];
        float* orow = out + (size_t)(pair >> 1) * H_ + c0 + m;
        atomicAdd(orow,      rw * acc[mt][0][r]);
        atomicAdd(orow + 16, rw * acc[mt][1][r]);
      }
    }
}

// ------------------------------------------------------------- launcher ----
extern "C" void kernel_launch(void* const* d_in, const int* in_sizes, int n_in,
                              void* d_out, int out_size, void* d_ws, size_t ws_size,
                              hipStream_t stream) {
  const float* X   = (const float*)d_in[0];
  const float* RW  = (const float*)d_in[1];
  const float* GUP = (const float*)d_in[2];
  const float* DWN = (const float*)d_in[3];
  const int*   SEL = (const int*)d_in[4];
  float* out = (float*)d_out;

  char* ws = (char*)d_ws;
  int* offs = (int*)ws;                                   // 64 B
  int* rows = (int*)(ws + 1024);                          // 8 KB
  unsigned short* Xb  = (unsigned short*)(ws + 16384);    // 4 MB bf16
  unsigned short* act = (unsigned short*)(ws + 16384 + 4194304);  // 3 MB bf16

  hipLaunchKernelGGL(prep_kernel, dim3(2049), dim3(256), 0, stream,
                     X, Xb, out, SEL, offs, rows);
  hipLaunchKernelGGL(fc1_mfma, dim3(48, 128), dim3(256), 0, stream,
                     Xb, GUP, offs, rows, act);
  hipLaunchKernelGGL(fc2_mfma, dim3(64, 128), dim3(256), 0, stream,
                     act, DWN, RW, offs, rows, out);
}

// Round 2
// 253.830 us; speedup vs baseline: 1.1051x; 1.1051x over previous
//
#include <hip/hip_runtime.h>
#include <math.h>

#define E_  8
#define H_  2048
#define I_  768
#define T_  1024
#define K_  2
#define TK_ 2048
#define GU_ 1536   // 2*I

typedef __bf16 bf16x8 __attribute__((ext_vector_type(8)));
typedef float  f32x4  __attribute__((ext_vector_type(4)));

static __device__ __forceinline__ short f2bf(float f) {
  union { float f; unsigned u; } v; v.f = f;
  unsigned r = (v.u + 0x7fffu + ((v.u >> 16) & 1u)) >> 16;
  return (short)r;
}

// pack two floats -> two bf16 in one u32 (round-half-up + v_perm)
static __device__ __forceinline__ unsigned pk2bf(float a, float b) {
  unsigned ua = __float_as_uint(a) + 0x8000u;
  unsigned ub = __float_as_uint(b) + 0x8000u;
  return __builtin_amdgcn_perm(ub, ua, 0x07060302u);  // lo=hi16(ua), hi=hi16(ub)
}

#define GLOAD_LDS16(g, l)                                                   \
  __builtin_amdgcn_global_load_lds(                                         \
      (const __attribute__((address_space(1))) void*)(g),                   \
      (__attribute__((address_space(3))) void*)(l), 16, 0, 0)

#define MFMA_BF16_16x16x32 __builtin_amdgcn_mfma_f32_16x16x32_bf16

// Fragment read: row-major [row][64], phys octet = oct ^ (row&7).
// Used for both A (128 rows) and B (64 rows) tiles.
static __device__ __forceinline__ bf16x8 frag_ld(const unsigned short* base,
                                                 int row, int oct) {
  return *(const bf16x8*)(base + row * 64 + ((oct ^ (row & 7)) * 8));
}

// Counted-vmcnt software pipeline step (T3/T4):
//  - raw s_barrier, NO vmcnt(0) drain: previous iter's 4 glls retired via
//    vmcnt(4) (the 4 in-flight vb loads stay outstanding across the barrier)
//  - A (global_load_lds): issue distance 1 (LDS dbuf)
//  - B (fp32->reg->bf16 LDS): issue distance 2 (vbA/vbB reg dbuf); the
//    reg->LDS writeB dependency is compiler-tracked (it emits its own wait)
//  - sched_barrier(0) pins gll-before-vb issue order so vmcnt(4) is exact
#define STEP(IT, VC, VN)                                                    \
  do {                                                                      \
    asm volatile("s_waitcnt vmcnt(4)" ::: "memory");                        \
    __builtin_amdgcn_s_barrier();                                           \
    __builtin_amdgcn_sched_barrier(0);                                      \
    int k1_ = ((IT) + 1 < niter ? (IT) + 1 : niter - 1) * 64;               \
    int k2_ = ((IT) + 2 < niter ? (IT) + 2 : niter - 1) * 64;               \
    issueA(cur ^ 1, k1_);                                                   \
    __builtin_amdgcn_sched_barrier(0);                                      \
    loadB(VN, k2_);                                                         \
    const unsigned short* a_ = &As[cur][0];                                 \
    const unsigned short* b_ = &Bs[cur][0];                                 \
    _Pragma("unroll")                                                       \
    for (int kk = 0; kk < 2; ++kk) {                                        \
      int o = kk * 4 + qf;                                                  \
      bf16x8 af0 = frag_ld(a_, w * 32 + m,      o);                         \
      bf16x8 af1 = frag_ld(a_, w * 32 + 16 + m, o);                         \
      bf16x8 b0  = frag_ld(b_, m,      o);                                  \
      bf16x8 b1  = frag_ld(b_, 16 + m, o);                                  \
      bf16x8 b2  = frag_ld(b_, 32 + m, o);                                  \
      bf16x8 b3  = frag_ld(b_, 48 + m, o);                                  \
      acc[0][0] = MFMA_BF16_16x16x32(af0, b0, acc[0][0], 0, 0, 0);          \
      acc[0][1] = MFMA_BF16_16x16x32(af0, b1, acc[0][1], 0, 0, 0);          \
      acc[0][2] = MFMA_BF16_16x16x32(af0, b2, acc[0][2], 0, 0, 0);          \
      acc[0][3] = MFMA_BF16_16x16x32(af0, b3, acc[0][3], 0, 0, 0);          \
      acc[1][0] = MFMA_BF16_16x16x32(af1, b0, acc[1][0], 0, 0, 0);          \
      acc[1][1] = MFMA_BF16_16x16x32(af1, b1, acc[1][1], 0, 0, 0);          \
      acc[1][2] = MFMA_BF16_16x16x32(af1, b2, acc[1][2], 0, 0, 0);          \
      acc[1][3] = MFMA_BF16_16x16x32(af1, b3, acc[1][3], 0, 0, 0);          \
    }                                                                       \
    writeB(cur ^ 1, VC);                                                    \
    asm volatile("s_waitcnt lgkmcnt(0)" ::: "memory");                      \
    __builtin_amdgcn_sched_barrier(0);                                      \
    cur ^= 1;                                                               \
  } while (0)

// --------------------------- prep: X cast + out zero + routing --------------
__global__ __launch_bounds__(256) void prep_kernel(
    const float* __restrict__ X, unsigned short* __restrict__ Xb,
    float* __restrict__ out,
    const int* __restrict__ sel, int* __restrict__ offs,
    int* __restrict__ rows) {
  __shared__ int cnt[E_], cur[E_], loff[E_ + 1];
  if (blockIdx.x < 2048) {
    int i = blockIdx.x * 256 + threadIdx.x;     // one float4 each (T*H/4 total)
    float4 v = ((const float4*)X)[i];
    unsigned p0 = pk2bf(v.x, v.y), p1 = pk2bf(v.z, v.w);
    ((uint2*)Xb)[i] = make_uint2(p0, p1);
    ((float4*)out)[i] = make_float4(0.f, 0.f, 0.f, 0.f);  // out: same elem count
    return;
  }
  int t = threadIdx.x;
  if (t < E_) { cnt[t] = 0; cur[t] = 0; }
  __syncthreads();
  for (int p = t; p < TK_; p += 256) atomicAdd(&cnt[sel[p]], 1);
  __syncthreads();
  if (t == 0) {
    int s = 0;
    for (int e = 0; e < E_; ++e) { loff[e] = s; s += cnt[e]; }
    loff[E_] = s;
  }
  __syncthreads();
  if (t <= E_) offs[t] = loff[t];
  for (int p = t; p < TK_; p += 256) {
    int e = sel[p];
    int pos = loff[e] + atomicAdd(&cur[e], 1);
    rows[pos] = p;
  }
}

// --------------------------------------------------- fc1 (MFMA) + swiglu ----
// BM=128 rows, BN=64 B-rows (32 gate + 32 up cols), BK=64.
// Counted-vmcnt pipeline (raw s_barrier, never drain). LDS 48KB -> 3 blk/CU.
// Grid: x = 24 (32 act cols each), y = 8 experts * 16 slots of 128 rows.
__global__ __launch_bounds__(256, 3) void fc1_mfma(
    const unsigned short* __restrict__ Xb, const float* __restrict__ GUP,
    const int* __restrict__ offs, const int* __restrict__ rows,
    unsigned short* __restrict__ act) {
  __shared__ __align__(16) unsigned short As[2][128 * 64];  // 32 KB
  __shared__ __align__(16) unsigned short Bs[2][64 * 64];   // 16 KB

  int e    = blockIdx.y >> 4;
  int rbeg = offs[e], rend = offs[e + 1];
  int row0 = rbeg + (blockIdx.y & 15) * 128;
  if (row0 >= rend) return;
  int c0 = blockIdx.x * 32;

  int tid = threadIdx.x, lane = tid & 63, w = tid >> 6;
  int rl  = lane >> 3;                    // 0..7
  int oct = (lane & 7) ^ rl;              // A-side global octet swizzle

  // A: wave w owns rows w*32 .. w*32+31, staged as 4 glls of 8 rows.
  const unsigned short* agp[4];
#pragma unroll
  for (int i = 0; i < 4; ++i) {
    int arow = row0 + w * 32 + i * 8 + rl;
    int aidx = arow < rend ? arow : rend - 1;
    agp[i] = Xb + (size_t)(rows[aidx] >> 1) * H_ + oct * 8;
  }
  auto issueA = [&](int buf, int k0) {
#pragma unroll
    for (int i = 0; i < 4; ++i)
      GLOAD_LDS16(agp[i] + k0, &As[buf][0] + (w * 32 + i * 8) * 64);
  };

  // B: thread covers k-quad kt x 4 consecutive n; n<32 gate, n>=32 up.
  int kt = tid >> 4, nt = tid & 15;
  int gbase = (nt < 8) ? (c0 + nt * 4) : (I_ + c0 + (nt - 8) * 4);
  const float* gupe = GUP + (size_t)e * H_ * GU_ + gbase;

  auto loadB = [&](float4 (&vb)[4], int k0) {
#pragma unroll
    for (int i = 0; i < 4; ++i)
      vb[i] = *(const float4*)(gupe + (size_t)(k0 + kt * 4 + i) * GU_);
  };
  auto writeB = [&](int buf, const float4 (&vb)[4]) {
#pragma unroll
    for (int j = 0; j < 4; ++j) {
      int n = nt * 4 + j;
      unsigned u0 = pk2bf(((const float*)&vb[0])[j], ((const float*)&vb[1])[j]);
      unsigned u1 = pk2bf(((const float*)&vb[2])[j], ((const float*)&vb[3])[j]);
      int phys = (kt >> 1) ^ (n & 7);
      *(uint2*)(&Bs[buf][0] + n * 64 + phys * 8 + (kt & 1) * 4) =
          make_uint2(u0, u1);
    }
  };

  int m = lane & 15, qf = lane >> 4;
  f32x4 acc[2][4] = {};
  float4 vbA[4], vbB[4];

  // prologue: stage A(0), B(0); put B(1) in flight
  issueA(0, 0);
  __builtin_amdgcn_sched_barrier(0);
  loadB(vbB, 0);
  writeB(0, vbB);                         // compiler waits vbB (drains glls too)
  loadB(vbA, 64);
  asm volatile("s_waitcnt lgkmcnt(0)" ::: "memory");
  __builtin_amdgcn_sched_barrier(0);

  const int niter = H_ / 64;              // 32 (even)
  int cur = 0;
#pragma unroll 1
  for (int it = 0; it < niter; it += 2) {
    STEP(it,     vbA, vbB);
    STEP(it + 1, vbB, vbA);
  }

  // epilogue: act = silu(gate)*up ; gate tiles 0,1 pair with up tiles 2,3.
#pragma unroll
  for (int mt = 0; mt < 2; ++mt)
#pragma unroll
    for (int g = 0; g < 2; ++g)
#pragma unroll
      for (int r = 0; r < 4; ++r) {
        int prow = row0 + w * 32 + mt * 16 + qf * 4 + r;
        if (prow < rend) {
          float gv = acc[mt][g][r], uv = acc[mt][g + 2][r];
          float a = gv / (1.0f + __expf(-gv)) * uv;
          act[(size_t)prow * I_ + c0 + g * 16 + m] = (unsigned short)f2bf(a);
        }
      }
}

// ------------------------------------- fc2 (MFMA) + fused weighted combine --
// BM=128, BN=64 out cols, BK=64; same counted-vmcnt pipeline.
// Grid: x = 32, y = 8 experts * 16 slots of 128 rows.
__global__ __launch_bounds__(256, 3) void fc2_mfma(
    const unsigned short* __restrict__ act, const float* __restrict__ DWN,
    const float* __restrict__ RW,
    const int* __restrict__ offs, const int* __restrict__ rows,
    float* __restrict__ out) {
  __shared__ __align__(16) unsigned short As[2][128 * 64];
  __shared__ __align__(16) unsigned short Bs[2][64 * 64];

  int e    = blockIdx.y >> 4;
  int rbeg = offs[e], rend = offs[e + 1];
  int row0 = rbeg + (blockIdx.y & 15) * 128;
  if (row0 >= rend) return;
  int c0 = blockIdx.x * 64;

  int tid = threadIdx.x, lane = tid & 63, w = tid >> 6;
  int rl  = lane >> 3;
  int oct = (lane & 7) ^ rl;

  const unsigned short* agp[4];
#pragma unroll
  for (int i = 0; i < 4; ++i) {
    int arow = row0 + w * 32 + i * 8 + rl;
    int aidx = arow < rend ? arow : rend - 1;
    agp[i] = act + (size_t)aidx * I_ + oct * 8;
  }
  auto issueA = [&](int buf, int k0) {
#pragma unroll
    for (int i = 0; i < 4; ++i)
      GLOAD_LDS16(agp[i] + k0, &As[buf][0] + (w * 32 + i * 8) * 64);
  };

  int kt = tid >> 4, nt = tid & 15;
  const float* dwe = DWN + (size_t)e * I_ * H_ + c0 + nt * 4;

  auto loadB = [&](float4 (&vb)[4], int k0) {
#pragma unroll
    for (int i = 0; i < 4; ++i)
      vb[i] = *(const float4*)(dwe + (size_t)(k0 + kt * 4 + i) * H_);
  };
  auto writeB = [&](int buf, const float4 (&vb)[4]) {
#pragma unroll
    for (int j = 0; j < 4; ++j) {
      int n = nt * 4 + j;
      unsigned u0 = pk2bf(((const float*)&vb[0])[j], ((const float*)&vb[1])[j]);
      unsigned u1 = pk2bf(((const float*)&vb[2])[j], ((const float*)&vb[3])[j]);
      int phys = (kt >> 1) ^ (n & 7);
      *(uint2*)(&Bs[buf][0] + n * 64 + phys * 8 + (kt & 1) * 4) =
          make_uint2(u0, u1);
    }
  };

  int m = lane & 15, qf = lane >> 4;
  f32x4 acc[2][4] = {};
  float4 vbA[4], vbB[4];

  issueA(0, 0);
  __builtin_amdgcn_sched_barrier(0);
  loadB(vbB, 0);
  writeB(0, vbB);
  loadB(vbA, 64);
  asm volatile("s_waitcnt lgkmcnt(0)" ::: "memory");
  __builtin_amdgcn_sched_barrier(0);

  const int niter = I_ / 64;              // 12 (even)
  int cur = 0;
#pragma unroll 1
  for (int it = 0; it < niter; it += 2) {
    STEP(it,     vbA, vbB);
    STEP(it + 1, vbB, vbA);
  }

  // epilogue: out[token] += rw * fc2  (out zeroed by prep)
#pragma unroll
  for (int mt = 0; mt < 2; ++mt)
#pragma unroll
    for (int r = 0; r < 4; ++r) {
      int prow = row0 + w * 32 + mt * 16 + qf * 4 + r;
      if (prow < rend) {
        int pair = rows[prow];
        float rw = RW[pair];
        float* orow = out + (size_t)(pair >> 1) * H_ + c0 + m;
#pragma unroll
        for (int ntile = 0; ntile < 4; ++ntile)
          atomicAdd(orow + ntile * 16, rw * acc[mt][ntile][r]);
      }
    }
}

// ------------------------------------------------------------- launcher ----
extern "C" void kernel_launch(void* const* d_in, const int* in_sizes, int n_in,
                              void* d_out, int out_size, void* d_ws, size_t ws_size,
                              hipStream_t stream) {
  const float* X   = (const float*)d_in[0];
  const float* RW  = (const float*)d_in[1];
  const float* GUP = (const float*)d_in[2];
  const float* DWN = (const float*)d_in[3];
  const int*   SEL = (const int*)d_in[4];
  float* out = (float*)d_out;

  char* ws = (char*)d_ws;
  int* offs = (int*)ws;                                   // 64 B
  int* rows = (int*)(ws + 1024);                          // 8 KB
  unsigned short* Xb  = (unsigned short*)(ws + 16384);    // 4 MB bf16
  unsigned short* act = (unsigned short*)(ws + 16384 + 4194304);  // 3 MB bf16

  hipLaunchKernelGGL(prep_kernel, dim3(2049), dim3(256), 0, stream,
                     X, Xb, out, SEL, offs, rows);
  hipLaunchKernelGGL(fc1_mfma, dim3(24, 128), dim3(256), 0, stream,
                     Xb, GUP, offs, rows, act);
  hipLaunchKernelGGL(fc2_mfma, dim3(32, 128), dim3(256), 0, stream,
                     act, DWN, RW, offs, rows, out);
}

// Round 4
// 251.103 us; speedup vs baseline: 1.1171x; 1.0109x over previous
//
#include <hip/hip_runtime.h>
#include <math.h>

#define E_  8
#define H_  2048
#define I_  768
#define T_  1024
#define K_  2
#define TK_ 2048
#define GU_ 1536   // 2*I

typedef __bf16 bf16x8 __attribute__((ext_vector_type(8)));
typedef float  f32x4  __attribute__((ext_vector_type(4)));

static __device__ __forceinline__ short f2bf(float f) {
  union { float f; unsigned u; } v; v.f = f;
  unsigned r = (v.u + 0x7fffu + ((v.u >> 16) & 1u)) >> 16;
  return (short)r;
}

// pack two floats -> two bf16 in one u32 (round-half-up + v_perm)
static __device__ __forceinline__ unsigned pk2bf(float a, float b) {
  unsigned ua = __float_as_uint(a) + 0x8000u;
  unsigned ub = __float_as_uint(b) + 0x8000u;
  return __builtin_amdgcn_perm(ub, ua, 0x07060302u);  // lo=hi16(ua), hi=hi16(ub)
}

#define GLOAD_LDS16(g, l)                                                   \
  __builtin_amdgcn_global_load_lds(                                         \
      (const __attribute__((address_space(1))) void*)(g),                   \
      (__attribute__((address_space(3))) void*)(l), 16, 0, 0)

#define MFMA_BF16_16x16x32 __builtin_amdgcn_mfma_f32_16x16x32_bf16

// A fragment read: row-major [row][64], phys octet = oct ^ (row&7).
static __device__ __forceinline__ bf16x8 frag_ld(const unsigned short* base,
                                                 int row, int oct) {
  return *(const bf16x8*)(base + row * 64 + ((oct ^ (row & 7)) * 8));
}

// B fragment read: [n][64], phys octet = o ^ (n&7) ^ (n>>3).
static __device__ __forceinline__ bf16x8 bfrag_ld(const unsigned short* base,
                                                  int n, int o) {
  int phys = (o ^ (n & 7) ^ (n >> 3)) & 7;
  return *(const bf16x8*)(base + n * 64 + phys * 8);
}

// Counted-vmcnt pipeline step, B reg budget = 2 iterations:
//  - vmcnt(4) at top retires prev iter's 4 glls AND the B-gen needed by this
//    step's writeB (loaded 2 iters ago); leaves last iter's B-gen in flight.
//  - issueA distance 1 (LDS dbuf); loadB reloads G for it+3 AFTER writeB(G)
//    consumed it (WAR on regs handled by dataflow) -> load->write distance 2.
#define STEP(IT, G)                                                         \
  do {                                                                      \
    asm volatile("s_waitcnt vmcnt(4)" ::: "memory");                        \
    __builtin_amdgcn_s_barrier();                                           \
    __builtin_amdgcn_sched_barrier(0);                                      \
    int k1_ = ((IT) + 1 < niter ? (IT) + 1 : niter - 1) * 64;               \
    int k3_ = ((IT) + 3 < niter ? (IT) + 3 : niter - 1) * 64;               \
    issueA(cur ^ 1, k1_);                                                   \
    __builtin_amdgcn_sched_barrier(0);                                      \
    const unsigned short* a_ = &As[cur][0];                                 \
    const unsigned short* b_ = &Bs[cur][0];                                 \
    __builtin_amdgcn_s_setprio(1);                                          \
    _Pragma("unroll")                                                       \
    for (int kk = 0; kk < 2; ++kk) {                                        \
      int o = kk * 4 + qf;                                                  \
      bf16x8 af0 = frag_ld(a_, w * 32 + m,      o);                         \
      bf16x8 af1 = frag_ld(a_, w * 32 + 16 + m, o);                         \
      bf16x8 b0  = bfrag_ld(b_, m,      o);                                 \
      bf16x8 b1  = bfrag_ld(b_, 16 + m, o);                                 \
      bf16x8 b2  = bfrag_ld(b_, 32 + m, o);                                 \
      bf16x8 b3  = bfrag_ld(b_, 48 + m, o);                                 \
      acc[0][0] = MFMA_BF16_16x16x32(af0, b0, acc[0][0], 0, 0, 0);          \
      acc[0][1] = MFMA_BF16_16x16x32(af0, b1, acc[0][1], 0, 0, 0);          \
      acc[0][2] = MFMA_BF16_16x16x32(af0, b2, acc[0][2], 0, 0, 0);          \
      acc[0][3] = MFMA_BF16_16x16x32(af0, b3, acc[0][3], 0, 0, 0);          \
      acc[1][0] = MFMA_BF16_16x16x32(af1, b0, acc[1][0], 0, 0, 0);          \
      acc[1][1] = MFMA_BF16_16x16x32(af1, b1, acc[1][1], 0, 0, 0);          \
      acc[1][2] = MFMA_BF16_16x16x32(af1, b2, acc[1][2], 0, 0, 0);          \
      acc[1][3] = MFMA_BF16_16x16x32(af1, b3, acc[1][3], 0, 0, 0);          \
    }                                                                       \
    __builtin_amdgcn_s_setprio(0);                                          \
    writeB(cur ^ 1, G);                                                     \
    loadB(G, k3_);                                                          \
    asm volatile("s_waitcnt lgkmcnt(0)" ::: "memory");                      \
    __builtin_amdgcn_sched_barrier(0);                                      \
    cur ^= 1;                                                               \
  } while (0)

// --------------------------- prep: X cast + routing (+inv map) --------------
__global__ __launch_bounds__(256) void prep_kernel(
    const float* __restrict__ X, unsigned short* __restrict__ Xb,
    float* __restrict__ out,
    const int* __restrict__ sel, int* __restrict__ offs,
    int* __restrict__ rows, int* __restrict__ inv, int zero_out) {
  __shared__ int cnt[E_], cur[E_], loff[E_ + 1];
  if (blockIdx.x < 2048) {
    int i = blockIdx.x * 256 + threadIdx.x;     // one float4 each (T*H/4 total)
    float4 v = ((const float4*)X)[i];
    unsigned p0 = pk2bf(v.x, v.y), p1 = pk2bf(v.z, v.w);
    ((uint2*)Xb)[i] = make_uint2(p0, p1);
    if (zero_out) ((float4*)out)[i] = make_float4(0.f, 0.f, 0.f, 0.f);
    return;
  }
  int t = threadIdx.x;
  if (t < E_) { cnt[t] = 0; cur[t] = 0; }
  __syncthreads();
  for (int p = t; p < TK_; p += 256) atomicAdd(&cnt[sel[p]], 1);
  __syncthreads();
  if (t == 0) {
    int s = 0;
    for (int e = 0; e < E_; ++e) { loff[e] = s; s += cnt[e]; }
    loff[E_] = s;
  }
  __syncthreads();
  if (t <= E_) offs[t] = loff[t];
  for (int p = t; p < TK_; p += 256) {
    int e = sel[p];
    int pos = loff[e] + atomicAdd(&cur[e], 1);
    rows[pos] = p;
    inv[p] = pos;
  }
}

// --------------------------------------------------- fc1 (MFMA) + swiglu ----
// BM=128 rows, BN=64 B-rows (32 gate + 32 up cols), BK=64.
// Counted-vmcnt pipeline, B reg budget 2 iters. LDS 48KB -> 3 blk/CU.
// Grid: x = 24 (32 act cols each), y = 8 experts * 16 slots of 128 rows.
__global__ __launch_bounds__(256, 3) void fc1_mfma(
    const unsigned short* __restrict__ Xb, const float* __restrict__ GUP,
    const int* __restrict__ offs, const int* __restrict__ rows,
    unsigned short* __restrict__ act) {
  __shared__ __align__(16) unsigned short As[2][128 * 64];  // 32 KB
  __shared__ __align__(16) unsigned short Bs[2][64 * 64];   // 16 KB

  int e    = blockIdx.y >> 4;
  int rbeg = offs[e], rend = offs[e + 1];
  int row0 = rbeg + (blockIdx.y & 15) * 128;
  if (row0 >= rend) return;
  int c0 = blockIdx.x * 32;

  int tid = threadIdx.x, lane = tid & 63, w = tid >> 6;
  int rl  = lane >> 3;                    // 0..7
  int oct = (lane & 7) ^ rl;              // A-side global octet swizzle

  // A: wave w owns rows w*32 .. w*32+31, staged as 4 glls of 8 rows.
  const unsigned short* agp[4];
#pragma unroll
  for (int i = 0; i < 4; ++i) {
    int arow = row0 + w * 32 + i * 8 + rl;
    int aidx = arow < rend ? arow : rend - 1;
    agp[i] = Xb + (size_t)(rows[aidx] >> 1) * H_ + oct * 8;
  }
  auto issueA = [&](int buf, int k0) {
#pragma unroll
    for (int i = 0; i < 4; ++i)
      GLOAD_LDS16(agp[i] + k0, &As[buf][0] + (w * 32 + i * 8) * 64);
  };

  // B: thread covers k-quad kt x 4 consecutive n; n<32 gate, n>=32 up.
  int kt = tid >> 4, nt = tid & 15;
  int gbase = (nt < 8) ? (c0 + nt * 4) : (I_ + c0 + (nt - 8) * 4);
  const float* gupe = GUP + (size_t)e * H_ * GU_ + gbase;

  auto loadB = [&](float4 (&vb)[4], int k0) {
#pragma unroll
    for (int i = 0; i < 4; ++i)
      vb[i] = *(const float4*)(gupe + (size_t)(k0 + kt * 4 + i) * GU_);
  };
  auto writeB = [&](int buf, const float4 (&vb)[4]) {
#pragma unroll
    for (int j = 0; j < 4; ++j) {
      int n = nt * 4 + j;
      unsigned u0 = pk2bf(((const float*)&vb[0])[j], ((const float*)&vb[1])[j]);
      unsigned u1 = pk2bf(((const float*)&vb[2])[j], ((const float*)&vb[3])[j]);
      int phys = ((kt >> 1) ^ (n & 7) ^ (n >> 3)) & 7;
      *(uint2*)(&Bs[buf][0] + n * 64 + phys * 8 + (kt & 1) * 4) =
          make_uint2(u0, u1);
    }
  };

  int m = lane & 15, qf = lane >> 4;
  f32x4 acc[2][4] = {};
  float4 vbA[4], vbB[4];

  // prologue: Bs[0]=k0; vbA holds k64 (STEP0), vbB holds k128 (STEP1)
  issueA(0, 0);
  __builtin_amdgcn_sched_barrier(0);
  loadB(vbA, 0);
  writeB(0, vbA);
  loadB(vbA, 64);
  loadB(vbB, 128);
  asm volatile("s_waitcnt lgkmcnt(0)" ::: "memory");
  __builtin_amdgcn_sched_barrier(0);

  const int niter = H_ / 64;              // 32 (even)
  int cur = 0;
#pragma unroll 1
  for (int it = 0; it < niter; it += 2) {
    STEP(it,     vbA);
    STEP(it + 1, vbB);
  }
  asm volatile("s_waitcnt vmcnt(0)" ::: "memory");  // drain tail glls (LDS safety)

  // epilogue: act = silu(gate)*up ; gate tiles 0,1 pair with up tiles 2,3.
#pragma unroll
  for (int mt = 0; mt < 2; ++mt)
#pragma unroll
    for (int g = 0; g < 2; ++g)
#pragma unroll
      for (int r = 0; r < 4; ++r) {
        int prow = row0 + w * 32 + mt * 16 + qf * 4 + r;
        if (prow < rend) {
          float gv = acc[mt][g][r], uv = acc[mt][g + 2][r];
          float a = gv / (1.0f + __expf(-gv)) * uv;
          act[(size_t)prow * I_ + c0 + g * 16 + m] = (unsigned short)f2bf(a);
        }
      }
}

// ------------------------------------- fc2 (MFMA), dual epilogue ------------
// BM=128, BN=64 out cols, BK=64; same pipeline.
// use_stage: weighted fp32 rows -> stage[TK][H] (no atomics; combine sums).
// else:      atomicAdd into out (fallback for small workspace).
// Grid: x = 32, y = 8 experts * 16 slots of 128 rows.
__global__ __launch_bounds__(256, 3) void fc2_mfma(
    const unsigned short* __restrict__ act, const float* __restrict__ DWN,
    const float* __restrict__ RW,
    const int* __restrict__ offs, const int* __restrict__ rows,
    float* __restrict__ stage, float* __restrict__ out, int use_stage) {
  __shared__ __align__(16) unsigned short As[2][128 * 64];
  __shared__ __align__(16) unsigned short Bs[2][64 * 64];

  int e    = blockIdx.y >> 4;
  int rbeg = offs[e], rend = offs[e + 1];
  int row0 = rbeg + (blockIdx.y & 15) * 128;
  if (row0 >= rend) return;
  int c0 = blockIdx.x * 64;

  int tid = threadIdx.x, lane = tid & 63, w = tid >> 6;
  int rl  = lane >> 3;
  int oct = (lane & 7) ^ rl;

  const unsigned short* agp[4];
#pragma unroll
  for (int i = 0; i < 4; ++i) {
    int arow = row0 + w * 32 + i * 8 + rl;
    int aidx = arow < rend ? arow : rend - 1;
    agp[i] = act + (size_t)aidx * I_ + oct * 8;
  }
  auto issueA = [&](int buf, int k0) {
#pragma unroll
    for (int i = 0; i < 4; ++i)
      GLOAD_LDS16(agp[i] + k0, &As[buf][0] + (w * 32 + i * 8) * 64);
  };

  int kt = tid >> 4, nt = tid & 15;
  const float* dwe = DWN + (size_t)e * I_ * H_ + c0 + nt * 4;

  auto loadB = [&](float4 (&vb)[4], int k0) {
#pragma unroll
    for (int i = 0; i < 4; ++i)
      vb[i] = *(const float4*)(dwe + (size_t)(k0 + kt * 4 + i) * H_);
  };
  auto writeB = [&](int buf, const float4 (&vb)[4]) {
#pragma unroll
    for (int j = 0; j < 4; ++j) {
      int n = nt * 4 + j;
      unsigned u0 = pk2bf(((const float*)&vb[0])[j], ((const float*)&vb[1])[j]);
      unsigned u1 = pk2bf(((const float*)&vb[2])[j], ((const float*)&vb[3])[j]);
      int phys = ((kt >> 1) ^ (n & 7) ^ (n >> 3)) & 7;
      *(uint2*)(&Bs[buf][0] + n * 64 + phys * 8 + (kt & 1) * 4) =
          make_uint2(u0, u1);
    }
  };

  int m = lane & 15, qf = lane >> 4;
  f32x4 acc[2][4] = {};
  float4 vbA[4], vbB[4];

  issueA(0, 0);
  __builtin_amdgcn_sched_barrier(0);
  loadB(vbA, 0);
  writeB(0, vbA);
  loadB(vbA, 64);
  loadB(vbB, 128);
  asm volatile("s_waitcnt lgkmcnt(0)" ::: "memory");
  __builtin_amdgcn_sched_barrier(0);

  const int niter = I_ / 64;              // 12 (even)
  int cur = 0;
#pragma unroll 1
  for (int it = 0; it < niter; it += 2) {
    STEP(it,     vbA);
    STEP(it + 1, vbB);
  }
  asm volatile("s_waitcnt vmcnt(0)" ::: "memory");

  // epilogue: weighted fp32, either staged (no atomics) or atomicAdd.
#pragma unroll
  for (int mt = 0; mt < 2; ++mt)
#pragma unroll
    for (int r = 0; r < 4; ++r) {
      int prow = row0 + w * 32 + mt * 16 + qf * 4 + r;
      if (prow < rend) {
        int pair = rows[prow];
        float rw = RW[pair];
        if (use_stage) {
          float* srow = stage + (size_t)prow * H_ + c0 + m;
          srow[0]  = rw * acc[mt][0][r];
          srow[16] = rw * acc[mt][1][r];
          srow[32] = rw * acc[mt][2][r];
          srow[48] = rw * acc[mt][3][r];
        } else {
          float* orow = out + (size_t)(pair >> 1) * H_ + c0 + m;
#pragma unroll
          for (int ntile = 0; ntile < 4; ++ntile)
            atomicAdd(orow + ntile * 16, rw * acc[mt][ntile][r]);
        }
      }
    }
}

// ------------------------- combine: out[t] = s[p0] + s[p1] ------------------
__global__ __launch_bounds__(256) void combine_kernel(
    const float* __restrict__ stage, const int* __restrict__ inv,
    float* __restrict__ out) {
  int idx = blockIdx.x * 256 + threadIdx.x;   // T*H/4 = 524288 total
  int t  = idx >> 9;                          // H/4 = 512 float4 per token
  int q  = idx & 511;
  int2 pp = *(const int2*)(inv + 2 * t);
  float4 a = ((const float4*)(stage + (size_t)pp.x * H_))[q];
  float4 b = ((const float4*)(stage + (size_t)pp.y * H_))[q];
  ((float4*)out)[idx] = make_float4(a.x + b.x, a.y + b.y, a.z + b.z, a.w + b.w);
}

// ------------------------------------------------------------- launcher ----
extern "C" void kernel_launch(void* const* d_in, const int* in_sizes, int n_in,
                              void* d_out, int out_size, void* d_ws, size_t ws_size,
                              hipStream_t stream) {
  const float* X   = (const float*)d_in[0];
  const float* RW  = (const float*)d_in[1];
  const float* GUP = (const float*)d_in[2];
  const float* DWN = (const float*)d_in[3];
  const int*   SEL = (const int*)d_in[4];
  float* out = (float*)d_out;

  char* ws = (char*)d_ws;
  int* offs = (int*)ws;                                   // 64 B
  int* rows = (int*)(ws + 1024);                          // 8 KB
  int* inv  = (int*)(ws + 16384);                         // 8 KB

  const size_t stage_bytes = (size_t)TK_ * H_ * 4;        // 16 MB
  const size_t act_bytes   = (size_t)TK_ * I_ * 2;        // 3 MB
  const size_t need_stage  = 32768 + stage_bytes + act_bytes;  // ~19.9 MB

  int use_stage = (ws_size >= need_stage) ? 1 : 0;
  unsigned short *Xb, *act;
  float* stage;
  if (use_stage) {
    // stage overlays Xb: Xb dies when fc1 finishes; stage born in fc2.
    stage = (float*)(ws + 32768);
    Xb    = (unsigned short*)(ws + 32768);
    act   = (unsigned short*)(ws + 32768 + stage_bytes);
  } else {
    stage = (float*)(ws + 32768);   // unused
    Xb    = (unsigned short*)(ws + 32768);
    act   = (unsigned short*)(ws + 32768 + 4194304);
  }

  hipLaunchKernelGGL(prep_kernel, dim3(2049), dim3(256), 0, stream,
                     X, Xb, out, SEL, offs, rows, inv, use_stage ? 0 : 1);
  hipLaunchKernelGGL(fc1_mfma, dim3(24, 128), dim3(256), 0, stream,
                     Xb, GUP, offs, rows, act);
  hipLaunchKernelGGL(fc2_mfma, dim3(32, 128), dim3(256), 0, stream,
                     act, DWN, RW, offs, rows, stage, out, use_stage);
  if (use_stage)
    hipLaunchKernelGGL(combine_kernel, dim3(2048), dim3(256), 0, stream,
                       stage, inv, out);
}